// Round 5
// baseline (402.262 us; speedup 1.0000x reference)
//
#include <hip/hip_runtime.h>

// VQ-VAE nearest-code lookup. N=65536 tokens, K=1024 codes, D=256, fp32 in/out.
// out layout (flat f32): values[N*256] | indices[N] (as float) | vectors[N*256]
//
// R8: single-scan candidate generation (phase B eliminated).
//  * Key insight: refine computes EXACT scores, so the candidate list only
//    needs to be a SUPERSET of {codes within MARGIN of final approx min}.
//    Emitting vs the RUNNING min during one scan gives that superset
//    (running_min >= final_min -> looser test). Per-stage 5-shfl butterfly
//    makes the running min global-so-far (per-lane-only mins would over-emit
//    ~10x). Halves MFMA/LDS/barrier work vs R7's two-phase (R7 MfmaUtil said
//    MFMA busy == exactly 2x-scan FLOPs: 28us; scan was ~2x its pipe floor).
//  * acc x2 dependency split: two 8-deep MFMA accumulator chains instead of
//    one 16-deep (same-acc dep chain was serializing the MFMA pipe).
//  * keep (proven): bijective LDS placement -> 0 bank conflicts; triple-
//    buffered global_load_lds + raw s_barrier + counted s_waitcnt vmcnt(4);
//    in-kernel refine from LDS list (exact fp32, u64 lex atomicMin).
//  * output split into vq_finish (pass3 clone): tiny LDS -> 8+ blocks/CU for
//    write streaming, and isolates phase timing in rocprof.
//  * order: prep, scan, cleanup, finish. cleanup (exact redo of overflow
//    rows) writes cand[] u64s; finish renders out from cand[]. Overflow list
//    owl lives in out's values region, which only finish (last) overwrites.
//
// Margin proof: |approx-exact| per score <= 2*2^-9*2*sum|a_i b_i| ~ 1.3 typ,
// <2.5 tail; candidate test needs MARGIN >= 2*err ~ 5; MARGIN=12 -> 2.4x slack.
// Superset argument: code c with exact-or-approx score within margin of the
// final min satisfies sc_c <= rmin_final + M <= rmin_running_at_c + M -> emitted.

constexpr int N_TOK = 65536;
constexpr int KC    = 1024;
constexpr int D     = 256;

constexpr size_t IDX_OFF = (size_t)N_TOK * D;   // 16777216 floats
constexpr size_t VEC_OFF = IDX_OFF + N_TOK;     // 16842752 floats
constexpr int    OWL_CAP = 1 << 20;             // overflow entries (in out region)

#define MARGIN 12.0f

typedef __attribute__((ext_vector_type(8)))  short bf16x8;
typedef __attribute__((ext_vector_type(16))) float f32x16;

__device__ inline unsigned short f2bf(float x) {
    unsigned int u = __float_as_uint(x);
    unsigned int r = (u + 0x7FFFu + ((u >> 16) & 1u)) >> 16;
    return (unsigned short)r;
}

__device__ inline unsigned int fkey(float f) {
    unsigned int b = __float_as_uint(f);
    return (b & 0x80000000u) ? ~b : (b | 0x80000000u);
}

// ---------------- prep: weight -> bf16, sqr, zero counter ----------------
__global__ __launch_bounds__(64)
void vq_prep(const float* __restrict__ w, unsigned short* __restrict__ wbf,
             float* __restrict__ sqr, int* __restrict__ cnt) {
    const int code = blockIdx.x;
    const int lane = threadIdx.x;
    float4 v = ((const float4*)w)[(size_t)code * 64 + lane];
    float s = v.x * v.x + v.y * v.y + v.z * v.z + v.w * v.w;
#pragma unroll
    for (int off = 32; off >= 1; off >>= 1) s += __shfl_xor(s, off, 64);
    unsigned short* d = wbf + (size_t)code * D + lane * 4;
    d[0] = f2bf(v.x); d[1] = f2bf(v.y); d[2] = f2bf(v.z); d[3] = f2bf(v.w);
    if (lane == 0) sqr[code] = s;
    if (code == 0 && lane == 0) *cnt = 0;
}

// ---------------- scan: single-pass filter + refine ----------------
constexpr int CT   = 32;        // codes per stage (16 KB per buffer)
constexpr int NSTG = KC / CT;   // 32 stages
constexpr int LCAP = 6144;

struct __align__(16) P1Shared {
    unsigned short sbuf[3][CT * D];  // 48 KB triple-buffered B tiles (permuted)
    float sqr[KC];                   // 4 KB
    int   list[LCAP];                // 24 KB
    unsigned long long lcand[128];   // 1 KB per-row (score,code) running min
    int   lcnt;
};                                   // ~77 KB -> 2 blocks/CU

// Stage CT codes into dstbuf. Dest linear (global_load_lds rule); SOURCE is
// permuted: slot s holds (code = s&31, kchunk = s>>5). Read side: frag kt of
// lane l sits at slot kt*64 + l  ->  base + lane*16, conflict-free b128.
__device__ __forceinline__ void stage_issue(const char* __restrict__ srcbase,
                                            unsigned short* __restrict__ dstbuf,
                                            const int (&soff)[4], int tid) {
#pragma unroll
    for (int r = 0; r < 4; ++r) {
        __builtin_amdgcn_global_load_lds(
            (const __attribute__((address_space(1))) void*)(srcbase + soff[r]),
            (__attribute__((address_space(3))) void*)(dstbuf + (tid + r * 256) * 8),
            16, 0, 0);
    }
}

// 512 blocks x 256 thr. Block: 128 rows x 1024 codes. Wave w: rows [w*32,+32).
__global__ __launch_bounds__(256, 2)
void vq_scan(const float* __restrict__ input, const float* __restrict__ weight,
             const unsigned short* __restrict__ wbf, const float* __restrict__ sqr,
             int* __restrict__ cnt, int* __restrict__ owl,
             unsigned long long* __restrict__ cand) {
    __shared__ P1Shared sh;

    const int tid  = threadIdx.x;
    const int wave = tid >> 6;
    const int lane = tid & 63;
    const int cl   = lane & 31;
    const int hi   = lane >> 5;
    const int row_base_blk = blockIdx.x * 128;
    const char* wbfB = (const char*)wbf;

    if (tid == 0) sh.lcnt = 0;
    if (tid < 128) sh.lcand[tid] = 0xFFFFFFFFFFFFFFFFULL;
    ((float4*)sh.sqr)[tid] = ((const float4*)sqr)[tid];   // 1024 f32 -> LDS

    // per-thread DMA source offsets within a 16 KB stage: slot = tid + r*256;
    // code = slot&31, kchunk = slot>>5; off = code*512 + kchunk*16 bytes.
    int soff[4];
#pragma unroll
    for (int r = 0; r < 4; ++r) {
        const int sl = tid + r * 256;
        soff[r] = (sl & 31) * 512 + (sl >> 5) * 16;
    }

    // A fragments, 32x32x16 shape: row = lane&31, k = kt*16 + hi*8 + j.
    // (Any shared A/B k-permutation cancels in the dot; C layout is verified.)
    bf16x8 afr[16];
    {
        const float* ar = input + (size_t)(row_base_blk + wave * 32 + cl) * D;
#pragma unroll
        for (int kt = 0; kt < 16; ++kt) {
            const int k0 = kt * 16 + hi * 8;
            float4 f0 = *(const float4*)(ar + k0);
            float4 f1 = *(const float4*)(ar + k0 + 4);
            bf16x8 v;
            v[0] = (short)f2bf(f0.x); v[1] = (short)f2bf(f0.y);
            v[2] = (short)f2bf(f0.z); v[3] = (short)f2bf(f0.w);
            v[4] = (short)f2bf(f1.x); v[5] = (short)f2bf(f1.y);
            v[6] = (short)f2bf(f1.z); v[7] = (short)f2bf(f1.w);
            afr[kt] = v;
        }
    }

    float rmin[16];
#pragma unroll
    for (int r = 0; r < 16; ++r) rmin[r] = 3.4e38f;

    __syncthreads();   // LDS init visible; full drain -> vmcnt clean at entry

    // prologue: 2 stages in flight (8 loads/thread)
    stage_issue(wbfB, sh.sbuf[0], soff, tid);
    stage_issue(wbfB + 16384, sh.sbuf[1], soff, tid);

    for (int s = 0; s < NSTG; ++s) {
        // counted wait: my 4 loads for buffer s are the oldest outstanding
        if (s == NSTG - 1) asm volatile("s_waitcnt vmcnt(0)" ::: "memory");
        else               asm volatile("s_waitcnt vmcnt(4)" ::: "memory");
        __builtin_amdgcn_sched_barrier(0);
        __builtin_amdgcn_s_barrier();          // raw barrier: no drain
        __builtin_amdgcn_sched_barrier(0);
        if (s + 2 < NSTG)
            stage_issue(wbfB + (s + 2) * 16384, sh.sbuf[(s + 2) % 3], soff, tid);

        const unsigned short* sb = sh.sbuf[s % 3] + (size_t)lane * 8;
        f32x16 acc0 = {0.f,0.f,0.f,0.f, 0.f,0.f,0.f,0.f,
                       0.f,0.f,0.f,0.f, 0.f,0.f,0.f,0.f};
        f32x16 acc1 = acc0;
#pragma unroll
        for (int h = 0; h < 2; ++h) {          // b live-range capped at 32 regs
            bf16x8 b[8];
#pragma unroll
            for (int kk = 0; kk < 8; ++kk)
                b[kk] = *(const bf16x8*)(sb + (h * 8 + kk) * 512);
#pragma unroll
            for (int kk = 0; kk < 4; ++kk) {   // two independent acc chains
                acc0 = __builtin_amdgcn_mfma_f32_32x32x16_bf16(afr[h*8 + 2*kk],     b[2*kk],     acc0, 0, 0, 0);
                acc1 = __builtin_amdgcn_mfma_f32_32x32x16_bf16(afr[h*8 + 2*kk + 1], b[2*kk + 1], acc1, 0, 0, 0);
            }
        }

        const int c0 = s * CT;
        const float sq = sh.sqr[c0 + cl];
#pragma unroll
        for (int r = 0; r < 16; ++r) {
            const float sc = sq - 2.0f * (acc0[r] + acc1[r]);
            // butterfly stage-min across the 32 code-lanes (xor<=16 stays in
            // the hi-group, whose lanes own the same rows), fold into rmin:
            float m = sc;
#pragma unroll
            for (int off = 1; off <= 16; off <<= 1)
                m = fminf(m, __shfl_xor(m, off, 64));
            rmin[r] = fminf(rmin[r], m);
            // emit vs running global-so-far min: superset of final candidates
            const bool flag = (sc <= rmin[r] + MARGIN);
            unsigned long long mask = __ballot(flag);
            if (mask) {
                const int leader = __builtin_ctzll(mask);
                const int nact   = __popcll(mask);
                const int prefix = __popcll(mask & ((1ULL << lane) - 1ULL));
                int wbase = 0;
                if (lane == leader) wbase = atomicAdd(&sh.lcnt, nact);
                wbase = __shfl(wbase, leader, 64);
                if (flag) {
                    // C layout (m74-verified): col=lane&31, row=(r&3)+8*(r>>2)+4*hi
                    const int lrow = wave * 32 + (r & 3) + 8 * (r >> 2) + 4 * hi;
                    const int pos  = wbase + prefix;
                    if (pos < LCAP) {
                        sh.list[pos] = (lrow << 10) | (c0 + cl);
                    } else {              // rare: global overflow list
                        int g = atomicAdd(cnt, 1);
                        if (g < OWL_CAP)
                            owl[g] = ((row_base_blk + lrow) << 10) | (c0 + cl);
                    }
                }
            }
        }
        asm volatile("s_waitcnt lgkmcnt(0)" ::: "memory");  // list/ds retired
        __builtin_amdgcn_sched_barrier(0);
    }

    __syncthreads();   // list complete across waves

    // ---- refine: exact fp32 dot per candidate, 16 lanes each ----
    {
        const int n  = min(sh.lcnt, LCAP);
        const int sw = tid >> 4;
        const int sl = tid & 15;
        const float4* in4 = (const float4*)input;
        const float4* w4  = (const float4*)weight;
        for (int e = sw; e < n; e += 16) {
            const int ent  = sh.list[e];
            const int lrow = ent >> 10;
            const int code = ent & 1023;
            const float4* zr = in4 + (size_t)(row_base_blk + lrow) * 64;
            const float4* wr = w4 + (size_t)code * 64;
            float s = 0.f;
#pragma unroll
            for (int j = 0; j < 4; ++j) {
                float4 za = zr[sl + 16 * j];
                float4 wa = wr[sl + 16 * j];
                s = fmaf(za.x, wa.x, s);
                s = fmaf(za.y, wa.y, s);
                s = fmaf(za.z, wa.z, s);
                s = fmaf(za.w, wa.w, s);
            }
#pragma unroll
            for (int off = 1; off <= 8; off <<= 1) s += __shfl_xor(s, off, 16);
            if (sl == 0) {
                const float score = sh.sqr[code] - 2.0f * s;
                unsigned long long key =
                    ((unsigned long long)fkey(score) << 32) | (unsigned int)code;
                atomicMin(&sh.lcand[lrow], key);
            }
        }
    }
    __syncthreads();

    if (tid < 128) cand[row_base_blk + tid] = sh.lcand[tid];
}

// ---------------- cleanup: exact redo of overflow rows -> cand[] ----------
__global__ __launch_bounds__(256)
void vq_cleanup(const float* __restrict__ input, const float* __restrict__ weight,
                const float* __restrict__ sqr, const int* __restrict__ owl,
                const int* __restrict__ cnt, unsigned long long* __restrict__ cand) {
    const int m = min(*cnt, OWL_CAP);
    if (m == 0) return;
    __shared__ float zrow[D];
    __shared__ unsigned long long best;
    const int tid = threadIdx.x;
    for (int e = blockIdx.x; e < m; e += gridDim.x) {
        const int grow = owl[e] >> 10;
        if (tid == 0) best = 0xFFFFFFFFFFFFFFFFULL;
        if (tid < 64) ((float4*)zrow)[tid] = ((const float4*)input)[(size_t)grow * 64 + tid];
        __syncthreads();
        for (int cc = 0; cc < 4; ++cc) {
            const int code = tid * 4 + cc;
            const float4* wr = (const float4*)weight + (size_t)code * 64;
            float s = 0.f;
            for (int k = 0; k < 64; ++k) {
                float4 wa = wr[k];
                s = fmaf(zrow[4 * k],     wa.x, s);
                s = fmaf(zrow[4 * k + 1], wa.y, s);
                s = fmaf(zrow[4 * k + 2], wa.z, s);
                s = fmaf(zrow[4 * k + 3], wa.w, s);
            }
            const float score = sqr[code] - 2.0f * s;
            unsigned long long key =
                ((unsigned long long)fkey(score) << 32) | (unsigned int)code;
            atomicMin(&best, key);
        }
        __syncthreads();
        if (tid == 0) cand[grow] = best;
        __syncthreads();
    }
}

// ---------------- finish: render outputs from cand[] ----------------
__global__ __launch_bounds__(256)
void vq_finish(const float* __restrict__ weight,
               const unsigned long long* __restrict__ cand,
               float* __restrict__ out) {
    __shared__ int fin[64];
    const int tid  = threadIdx.x;
    const int row0 = blockIdx.x * 64;
    if (tid < 64) {
        int idx = (int)(cand[row0 + tid] & 1023ULL);
        fin[tid] = idx;
        out[IDX_OFF + row0 + tid] = (float)idx;
    }
    __syncthreads();
    const float4* w4 = (const float4*)weight;
    float4* out4 = (float4*)out;
#pragma unroll
    for (int k = 0; k < 16; ++k) {
        int i = tid + k * 256;
        int r = i >> 6, q = i & 63;
        float4 v = w4[(size_t)fin[r] * 64 + q];
        size_t o = (size_t)(row0 + r) * 64 + q;
        out4[o] = v;                    // values
        out4[VEC_OFF / 4 + o] = v;      // vectors
    }
}

extern "C" void kernel_launch(void* const* d_in, const int* in_sizes, int n_in,
                              void* d_out, int out_size, void* d_ws, size_t ws_size,
                              hipStream_t stream) {
    const float* input  = (const float*)d_in[0];   // [64,32,32,256] f32
    const float* weight = (const float*)d_in[1];   // [1024,256] f32
    float* out = (float*)d_out;

    // ws layout (~1.04 MB)
    unsigned short* wbf = (unsigned short*)d_ws;                            // 512 KB
    float* sqr = (float*)((char*)d_ws + 524288);                            // 4 KB
    int*   cnt = (int*)((char*)d_ws + 528384);                              // 4 B
    unsigned long long* cand = (unsigned long long*)((char*)d_ws + 532480); // 512 KB

    // overflow list lives in out's values region; cleanup reads it BEFORE
    // finish (the only writer of out) runs.
    int* owl = (int*)out;

    vq_prep   <<<KC, 64, 0, stream>>>(weight, wbf, sqr, cnt);
    vq_scan   <<<N_TOK / 128, 256, 0, stream>>>(input, weight, wbf, sqr, cnt, owl, cand);
    vq_cleanup<<<256, 256, 0, stream>>>(input, weight, sqr, owl, cnt, cand);
    vq_finish <<<N_TOK / 64, 256, 0, stream>>>(weight, cand, out);
}

// Round 6
// 305.097 us; speedup vs baseline: 1.3185x; 1.3185x over previous
//
#include <hip/hip_runtime.h>

// VQ-VAE nearest-code lookup. N=65536 tokens, K=1024 codes, D=256, fp32 in/out.
// out layout (flat f32): values[N*256] | indices[N] (as float) | vectors[N*256]
//
// R9: swapped-operand MFMA (T12 trick: make the reduction axis lane-local).
//  * R8 post-mortem: VGPR 88 (vs ~160 live) -> remat/spill (FETCH +95MB) from
//    acc x2 + per-r butterfly temps; 80 shfl/stage on the DS pipe serialized
//    every emission. Fix: compute mfma(codes_as_A, tokens_as_B) so C cols =
//    tokens (lane), C regs = 16 codes. Per-token stage-min = 15 in-lane v_min
//    + ONE shfl_xor(32); running min = 1 reg (was 16). Single acc chain.
//    LDS layout + token fragments identical to R7; only operand order and
//    emission indexing change. sqr per-reg (per-code) comes from a permuted
//    copy sqrp (prep writes it) read as 4 uniform float4 LDS broadcasts/stage.
//  * single-scan candidate generation kept (R8's valid half): emit vs running
//    global-so-far min; refine computes EXACT scores so the list only needs
//    to be a superset of {codes within MARGIN of final approx min}:
//    sc_c <= rmin_final + M <= rmin_running_at_c + M -> emitted. Stage min is
//    folded into rmin BEFORE the flag test (tightest valid threshold).
//  * kept (proven): bijective LDS placement (slot = kchunk*32 + code; every
//    ds_read_b128 is base + lane*16 -> 0 bank conflicts, verified R6b-R8);
//    triple-buffered global_load_lds + raw s_barrier + counted vmcnt(4)
//    (all waves pass their own vmcnt(4) before the stage barrier -> every
//    load for buffer s has landed before anyone reads it); in-kernel refine
//    (exact fp32, u64 lex atomicMin == np.argmin tie-break); separate
//    high-occupancy vq_finish for the 128MB output stream.
//  * order: prep, scan, cleanup, finish. cleanup (exact redo of overflow
//    rows, normally 0) writes cand[]; owl lives in out's values region,
//    overwritten only by finish (last).
//
// Margin proof: |approx-exact| per score <= 2*2^-9*2*sum|a_i b_i| ~ 1.3 typ,
// <2.5 tail; candidate test needs MARGIN >= 2*err ~ 5; MARGIN=12 -> 2.4x slack.

constexpr int N_TOK = 65536;
constexpr int KC    = 1024;
constexpr int D     = 256;

constexpr size_t IDX_OFF = (size_t)N_TOK * D;   // 16777216 floats
constexpr size_t VEC_OFF = IDX_OFF + N_TOK;     // 16842752 floats
constexpr int    OWL_CAP = 1 << 20;             // overflow entries (in out region)

#define MARGIN 12.0f

typedef __attribute__((ext_vector_type(8)))  short bf16x8;
typedef __attribute__((ext_vector_type(16))) float f32x16;

__device__ inline unsigned short f2bf(float x) {
    unsigned int u = __float_as_uint(x);
    unsigned int r = (u + 0x7FFFu + ((u >> 16) & 1u)) >> 16;
    return (unsigned short)r;
}

__device__ inline unsigned int fkey(float f) {
    unsigned int b = __float_as_uint(f);
    return (b & 0x80000000u) ? ~b : (b | 0x80000000u);
}

// ---------------- prep: weight -> bf16, sqr + permuted sqrp, zero cnt ------
// sqrp permutation: code c = s*32 + w, w = (r&3) + 4*hi + 8*(r>>2)  ->
// sqrp[s*32 + hi*16 + r] = sqr[c], so scan reg r of half hi reads sqrp
// linearly: r = (w&3) + 4*(w>>3), hi = (w>>2)&1.
__global__ __launch_bounds__(64)
void vq_prep(const float* __restrict__ w, unsigned short* __restrict__ wbf,
             float* __restrict__ sqr, float* __restrict__ sqrp,
             int* __restrict__ cnt) {
    const int code = blockIdx.x;
    const int lane = threadIdx.x;
    float4 v = ((const float4*)w)[(size_t)code * 64 + lane];
    float s = v.x * v.x + v.y * v.y + v.z * v.z + v.w * v.w;
#pragma unroll
    for (int off = 32; off >= 1; off >>= 1) s += __shfl_xor(s, off, 64);
    unsigned short* d = wbf + (size_t)code * D + lane * 4;
    d[0] = f2bf(v.x); d[1] = f2bf(v.y); d[2] = f2bf(v.z); d[3] = f2bf(v.w);
    if (lane == 0) {
        sqr[code] = s;
        const int wi = code & 31;
        const int dest = (code >> 5) * 32 + ((wi >> 2) & 1) * 16
                       + (wi & 3) + 4 * (wi >> 3);
        sqrp[dest] = s;
    }
    if (code == 0 && lane == 0) *cnt = 0;
}

// ---------------- scan: single-pass filter + refine ----------------
constexpr int CT   = 32;        // codes per stage (16 KB per buffer)
constexpr int NSTG = KC / CT;   // 32 stages
constexpr int LCAP = 5120;

struct __align__(16) P1Shared {
    unsigned short sbuf[3][CT * D];  // 48 KB triple-buffered B tiles (permuted)
    float sqr[KC];                   // 4 KB (refine)
    float sqrp[KC];                  // 4 KB (scan, permuted)
    int   list[LCAP];                // 20 KB
    unsigned long long lcand[128];   // 1 KB per-row (score,code) running min
    int   lcnt;
};                                   // ~78.9 KB -> 2 blocks/CU

// Stage CT codes into dstbuf. Dest linear (global_load_lds rule); SOURCE is
// permuted: slot s holds (code = s&31, kchunk = s>>5). Read side: frag kt of
// lane l sits at slot kt*64 + l  ->  base + lane*16, conflict-free b128.
__device__ __forceinline__ void stage_issue(const char* __restrict__ srcbase,
                                            unsigned short* __restrict__ dstbuf,
                                            const int (&soff)[4], int tid) {
#pragma unroll
    for (int r = 0; r < 4; ++r) {
        __builtin_amdgcn_global_load_lds(
            (const __attribute__((address_space(1))) void*)(srcbase + soff[r]),
            (__attribute__((address_space(3))) void*)(dstbuf + (tid + r * 256) * 8),
            16, 0, 0);
    }
}

// 512 blocks x 256 thr. Block: 128 rows x 1024 codes. Wave w: rows [w*32,+32).
__global__ __launch_bounds__(256, 2)
void vq_scan(const float* __restrict__ input, const float* __restrict__ weight,
             const unsigned short* __restrict__ wbf, const float* __restrict__ sqr,
             const float* __restrict__ sqrp,
             int* __restrict__ cnt, int* __restrict__ owl,
             unsigned long long* __restrict__ cand) {
    __shared__ P1Shared sh;

    const int tid  = threadIdx.x;
    const int wave = tid >> 6;
    const int lane = tid & 63;
    const int cl   = lane & 31;
    const int hi   = lane >> 5;
    const int row_base_blk = blockIdx.x * 128;
    const char* wbfB = (const char*)wbf;

    if (tid == 0) sh.lcnt = 0;
    if (tid < 128) sh.lcand[tid] = 0xFFFFFFFFFFFFFFFFULL;
    ((float4*)sh.sqr)[tid]  = ((const float4*)sqr)[tid];    // 1024 f32 -> LDS
    ((float4*)sh.sqrp)[tid] = ((const float4*)sqrp)[tid];   // permuted copy

    // per-thread DMA source offsets within a 16 KB stage: slot = tid + r*256;
    // code = slot&31, kchunk = slot>>5; off = code*512 + kchunk*16 bytes.
    int soff[4];
#pragma unroll
    for (int r = 0; r < 4; ++r) {
        const int sl = tid + r * 256;
        soff[r] = (sl & 31) * 512 + (sl >> 5) * 16;
    }

    // Token fragments (B-operand), 32x32x16: col = lane&31, k = kt*16 + hi*8 + j.
    bf16x8 afr[16];
    {
        const float* ar = input + (size_t)(row_base_blk + wave * 32 + cl) * D;
#pragma unroll
        for (int kt = 0; kt < 16; ++kt) {
            const int k0 = kt * 16 + hi * 8;
            float4 f0 = *(const float4*)(ar + k0);
            float4 f1 = *(const float4*)(ar + k0 + 4);
            bf16x8 v;
            v[0] = (short)f2bf(f0.x); v[1] = (short)f2bf(f0.y);
            v[2] = (short)f2bf(f0.z); v[3] = (short)f2bf(f0.w);
            v[4] = (short)f2bf(f1.x); v[5] = (short)f2bf(f1.y);
            v[6] = (short)f2bf(f1.z); v[7] = (short)f2bf(f1.w);
            afr[kt] = v;
        }
    }

    float rmin = 3.4e38f;   // running approx min for this lane's token

    __syncthreads();   // LDS init visible; full drain -> vmcnt clean at entry

    // prologue: 2 stages in flight (8 loads/thread)
    stage_issue(wbfB, sh.sbuf[0], soff, tid);
    stage_issue(wbfB + 16384, sh.sbuf[1], soff, tid);

    for (int s = 0; s < NSTG; ++s) {
        // counted wait: my 4 loads for buffer s are the oldest outstanding;
        // all waves pass their own wait before the barrier -> buffer s ready.
        if (s == NSTG - 1) asm volatile("s_waitcnt vmcnt(0)" ::: "memory");
        else               asm volatile("s_waitcnt vmcnt(4)" ::: "memory");
        __builtin_amdgcn_sched_barrier(0);
        __builtin_amdgcn_s_barrier();          // raw barrier: no drain
        __builtin_amdgcn_sched_barrier(0);
        if (s + 2 < NSTG)
            stage_issue(wbfB + (s + 2) * 16384, sh.sbuf[(s + 2) % 3], soff, tid);

        // codes as A-operand: lane -> row(code) = lane&31, k = kt*16 + hi*8 + j
        // (same LDS pattern as R7; operands swapped in the intrinsic call).
        const unsigned short* sb = sh.sbuf[s % 3] + (size_t)lane * 8;
        f32x16 acc = {0.f,0.f,0.f,0.f, 0.f,0.f,0.f,0.f,
                      0.f,0.f,0.f,0.f, 0.f,0.f,0.f,0.f};
#pragma unroll
        for (int h = 0; h < 2; ++h) {          // b live-range capped at 32 regs
            bf16x8 b[8];
#pragma unroll
            for (int kk = 0; kk < 8; ++kk)
                b[kk] = *(const bf16x8*)(sb + (h * 8 + kk) * 512);
#pragma unroll
            for (int kk = 0; kk < 8; ++kk)
                acc = __builtin_amdgcn_mfma_f32_32x32x16_bf16(b[kk], afr[h * 8 + kk], acc, 0, 0, 0);
        }

        // sqrp broadcast reads: 16 f32, uniform within each hi half-wave.
        const int c0 = s * CT;
        const float4* sp = (const float4*)(sh.sqrp + c0 + hi * 16);
        float4 q0 = sp[0], q1 = sp[1], q2 = sp[2], q3 = sp[3];
        float sc[16];
        sc[0]=q0.x-2.0f*acc[0];  sc[1]=q0.y-2.0f*acc[1];
        sc[2]=q0.z-2.0f*acc[2];  sc[3]=q0.w-2.0f*acc[3];
        sc[4]=q1.x-2.0f*acc[4];  sc[5]=q1.y-2.0f*acc[5];
        sc[6]=q1.z-2.0f*acc[6];  sc[7]=q1.w-2.0f*acc[7];
        sc[8]=q2.x-2.0f*acc[8];  sc[9]=q2.y-2.0f*acc[9];
        sc[10]=q2.z-2.0f*acc[10]; sc[11]=q2.w-2.0f*acc[11];
        sc[12]=q3.x-2.0f*acc[12]; sc[13]=q3.y-2.0f*acc[13];
        sc[14]=q3.z-2.0f*acc[14]; sc[15]=q3.w-2.0f*acc[15];

        // per-token stage min: in-lane tree + one cross-half swap
        float m = fminf(fminf(fminf(sc[0], sc[1]), fminf(sc[2], sc[3])),
                        fminf(fminf(sc[4], sc[5]), fminf(sc[6], sc[7])));
        m = fminf(m, fminf(fminf(fminf(sc[8], sc[9]), fminf(sc[10], sc[11])),
                           fminf(fminf(sc[12], sc[13]), fminf(sc[14], sc[15]))));
        m = fminf(m, __shfl_xor(m, 32, 64));
        rmin = fminf(rmin, m);
        const float thr = rmin + MARGIN;

        // emit vs running global-so-far min: superset of final candidates
        const int lrow = wave * 32 + cl;
#pragma unroll
        for (int r = 0; r < 16; ++r) {
            const bool flag = (sc[r] <= thr);
            unsigned long long mask = __ballot(flag);
            if (mask) {
                const int leader = __builtin_ctzll(mask);
                const int nact   = __popcll(mask);
                const int prefix = __popcll(mask & ((1ULL << lane) - 1ULL));
                int wbase = 0;
                if (lane == leader) wbase = atomicAdd(&sh.lcnt, nact);
                wbase = __shfl(wbase, leader, 64);
                if (flag) {
                    // C layout (m74-verified): col=lane&31 (token),
                    // row (code) = (r&3) + 8*(r>>2) + 4*hi
                    const int code = c0 + (r & 3) + 8 * (r >> 2) + 4 * hi;
                    const int pos  = wbase + prefix;
                    if (pos < LCAP) {
                        sh.list[pos] = (lrow << 10) | code;
                    } else {              // rare: global overflow list
                        int g = atomicAdd(cnt, 1);
                        if (g < OWL_CAP)
                            owl[g] = ((row_base_blk + lrow) << 10) | code;
                    }
                }
            }
        }
    }

    __syncthreads();   // list complete across waves

    // ---- refine: exact fp32 dot per candidate, 16 lanes each ----
    {
        const int n  = min(sh.lcnt, LCAP);
        const int sw = tid >> 4;
        const int sl = tid & 15;
        const float4* in4 = (const float4*)input;
        const float4* w4  = (const float4*)weight;
        for (int e = sw; e < n; e += 16) {
            const int ent  = sh.list[e];
            const int lrow = ent >> 10;
            const int code = ent & 1023;
            const float4* zr = in4 + (size_t)(row_base_blk + lrow) * 64;
            const float4* wr = w4 + (size_t)code * 64;
            float s = 0.f;
#pragma unroll
            for (int j = 0; j < 4; ++j) {
                float4 za = zr[sl + 16 * j];
                float4 wa = wr[sl + 16 * j];
                s = fmaf(za.x, wa.x, s);
                s = fmaf(za.y, wa.y, s);
                s = fmaf(za.z, wa.z, s);
                s = fmaf(za.w, wa.w, s);
            }
#pragma unroll
            for (int off = 1; off <= 8; off <<= 1) s += __shfl_xor(s, off, 16);
            if (sl == 0) {
                const float score = sh.sqr[code] - 2.0f * s;
                unsigned long long key =
                    ((unsigned long long)fkey(score) << 32) | (unsigned int)code;
                atomicMin(&sh.lcand[lrow], key);
            }
        }
    }
    __syncthreads();

    if (tid < 128) cand[row_base_blk + tid] = sh.lcand[tid];
}

// ---------------- cleanup: exact redo of overflow rows -> cand[] ----------
__global__ __launch_bounds__(256)
void vq_cleanup(const float* __restrict__ input, const float* __restrict__ weight,
                const float* __restrict__ sqr, const int* __restrict__ owl,
                const int* __restrict__ cnt, unsigned long long* __restrict__ cand) {
    const int m = min(*cnt, OWL_CAP);
    if (m == 0) return;
    __shared__ float zrow[D];
    __shared__ unsigned long long best;
    const int tid = threadIdx.x;
    for (int e = blockIdx.x; e < m; e += gridDim.x) {
        const int grow = owl[e] >> 10;
        if (tid == 0) best = 0xFFFFFFFFFFFFFFFFULL;
        if (tid < 64) ((float4*)zrow)[tid] = ((const float4*)input)[(size_t)grow * 64 + tid];
        __syncthreads();
        for (int cc = 0; cc < 4; ++cc) {
            const int code = tid * 4 + cc;
            const float4* wr = (const float4*)weight + (size_t)code * 64;
            float s = 0.f;
            for (int k = 0; k < 64; ++k) {
                float4 wa = wr[k];
                s = fmaf(zrow[4 * k],     wa.x, s);
                s = fmaf(zrow[4 * k + 1], wa.y, s);
                s = fmaf(zrow[4 * k + 2], wa.z, s);
                s = fmaf(zrow[4 * k + 3], wa.w, s);
            }
            const float score = sqr[code] - 2.0f * s;
            unsigned long long key =
                ((unsigned long long)fkey(score) << 32) | (unsigned int)code;
            atomicMin(&best, key);
        }
        __syncthreads();
        if (tid == 0) cand[grow] = best;
        __syncthreads();
    }
}

// ---------------- finish: render outputs from cand[] ----------------
__global__ __launch_bounds__(256)
void vq_finish(const float* __restrict__ weight,
               const unsigned long long* __restrict__ cand,
               float* __restrict__ out) {
    __shared__ int fin[64];
    const int tid  = threadIdx.x;
    const int row0 = blockIdx.x * 64;
    if (tid < 64) {
        int idx = (int)(cand[row0 + tid] & 1023ULL);
        fin[tid] = idx;
        out[IDX_OFF + row0 + tid] = (float)idx;
    }
    __syncthreads();
    const float4* w4 = (const float4*)weight;
    float4* out4 = (float4*)out;
#pragma unroll
    for (int k = 0; k < 16; ++k) {
        int i = tid + k * 256;
        int r = i >> 6, q = i & 63;
        float4 v = w4[(size_t)fin[r] * 64 + q];
        size_t o = (size_t)(row0 + r) * 64 + q;
        out4[o] = v;                    // values
        out4[VEC_OFF / 4 + o] = v;      // vectors
    }
}

extern "C" void kernel_launch(void* const* d_in, const int* in_sizes, int n_in,
                              void* d_out, int out_size, void* d_ws, size_t ws_size,
                              hipStream_t stream) {
    const float* input  = (const float*)d_in[0];   // [64,32,32,256] f32
    const float* weight = (const float*)d_in[1];   // [1024,256] f32
    float* out = (float*)d_out;

    // ws layout (~1.05 MB)
    unsigned short* wbf = (unsigned short*)d_ws;                            // 512 KB
    float* sqr  = (float*)((char*)d_ws + 524288);                           // 4 KB
    float* sqrp = (float*)((char*)d_ws + 528384);                           // 4 KB
    int*   cnt  = (int*)((char*)d_ws + 532480);                             // 4 B (4 KB slot)
    unsigned long long* cand = (unsigned long long*)((char*)d_ws + 536576); // 512 KB

    // overflow list lives in out's values region; cleanup reads it BEFORE
    // finish (the only writer of out) runs.
    int* owl = (int*)out;

    vq_prep   <<<KC, 64, 0, stream>>>(weight, wbf, sqr, sqrp, cnt);
    vq_scan   <<<N_TOK / 128, 256, 0, stream>>>(input, weight, wbf, sqr, sqrp, cnt, owl, cand);
    vq_cleanup<<<256, 256, 0, stream>>>(input, weight, sqr, owl, cnt, cand);
    vq_finish <<<N_TOK / 64, 256, 0, stream>>>(weight, cand, out);
}

// Round 7
// 283.768 us; speedup vs baseline: 1.4176x; 1.0752x over previous
//
#include <hip/hip_runtime.h>

// VQ-VAE nearest-code lookup. N=65536 tokens, K=1024 codes, D=256, fp32 in/out.
// out layout (flat f32): values[N*256] | indices[N] (as float) | vectors[N*256]
//
// R10 (on R9's verified core: swapped-operand MFMA so reduction axis is
// lane-local; bijective LDS placement -> 0 bank conflicts; one-ahead DMA
// prefetch; single-scan running-min superset emission + exact fp32 refine):
//  * skip-filter refine: entry = skey16|cl5|code10 (skey = fkey(sc)>>16,
//    monotone, quantum ~2 at |score|~256; row implied by per-wave segment).
//    After the loop, tk[row] = (fkey(rmin_final+MARGIN)>>16)+1; refine skips
//    entries above it (~15cy vs ~600cy) -> over-emitted (~2.5x) loose set
//    costs almost nothing; HBM re-gather drops to the tight set.
//    (R9 FETCH 190MB = 3x input was refine re-reads, not spill: VGPR 96 with
//    WRITE clean.)
//  * ballot-free emission: per-lane 16b flag mask + 6-step shfl prefix scan +
//    register-resident per-wave cursor (no LDS atomics in the loop, all sc[]
//    indexing static). R9: 16 serial ballot rounds/stage/wave ~400cy + jitter.
//  * CT=64, 512-thr blocks, 256 rows, grid=256 (=CU count; LDS 117KB forces
//    1 block/CU -> even spread): halves barrier rounds (16) and per-CU L2
//    staging traffic; two independent MFMA chains (one per 32-code tile).
//    One-stage-ahead prefetch + ~2000cy stages -> plain __syncthreads() per
//    stage is cheap (loads long landed); counted-vmcnt asm no longer needed.
//  * order: prep, scan, cleanup, finish. Overflow (per-wave list > WCAP,
//    ~3x headroom) -> global owl; cleanup exactly recomputes those rows.
//    owl lives in out's values region, overwritten only by finish (last).
//
// Margin proof: |approx-exact| per score <= 2*2^-9*2*sum|a_i b_i| ~ 1.3 typ,
// <2.5 tail; candidate test needs MARGIN >= 2*err ~ 5; MARGIN=12 -> 2.4x
// slack. Superset argument: sc_c <= rmin_final + M <= rmin_running_at_c + M.
// Filter keeps exactly {skey <= tk} >= {sc <= rmin_final + M} (monotone key,
// +1 quantum slack) -> no false rejects.

constexpr int N_TOK = 65536;
constexpr int KC    = 1024;
constexpr int D     = 256;

constexpr size_t IDX_OFF = (size_t)N_TOK * D;   // 16777216 floats
constexpr size_t VEC_OFF = IDX_OFF + N_TOK;     // 16842752 floats
constexpr int    OWL_CAP = 1 << 20;             // overflow entries (in out region)

#define MARGIN 12.0f

typedef __attribute__((ext_vector_type(8)))  short bf16x8;
typedef __attribute__((ext_vector_type(16))) float f32x16;

__device__ inline unsigned short f2bf(float x) {
    unsigned int u = __float_as_uint(x);
    unsigned int r = (u + 0x7FFFu + ((u >> 16) & 1u)) >> 16;
    return (unsigned short)r;
}

__device__ inline unsigned int fkey(float f) {
    unsigned int b = __float_as_uint(f);
    return (b & 0x80000000u) ? ~b : (b | 0x80000000u);
}

// ---------------- prep: weight -> bf16, sqr + permuted sqrp, zero cnt ------
// sqrp: for any 32-aligned tile, code c = base + w, w = (r&3) + 4*hi + 8*(r>>2)
// -> sqrp[base + hi*16 + r] = sqr[c]; scan reg r of half hi reads linearly.
__global__ __launch_bounds__(64)
void vq_prep(const float* __restrict__ w, unsigned short* __restrict__ wbf,
             float* __restrict__ sqr, float* __restrict__ sqrp,
             int* __restrict__ cnt) {
    const int code = blockIdx.x;
    const int lane = threadIdx.x;
    float4 v = ((const float4*)w)[(size_t)code * 64 + lane];
    float s = v.x * v.x + v.y * v.y + v.z * v.z + v.w * v.w;
#pragma unroll
    for (int off = 32; off >= 1; off >>= 1) s += __shfl_xor(s, off, 64);
    unsigned short* d = wbf + (size_t)code * D + lane * 4;
    d[0] = f2bf(v.x); d[1] = f2bf(v.y); d[2] = f2bf(v.z); d[3] = f2bf(v.w);
    if (lane == 0) {
        sqr[code] = s;
        const int wi = code & 31;
        const int dest = (code & ~31) + ((wi >> 2) & 1) * 16
                       + (wi & 3) + 4 * (wi >> 3);
        sqrp[dest] = s;
    }
    if (code == 0 && lane == 0) *cnt = 0;
}

// ---------------- scan: single-pass filter + skip-filtered refine ----------
constexpr int CT   = 64;        // codes per stage (32 KB per buffer)
constexpr int NSTG = KC / CT;   // 16 stages
constexpr int WCAP = 1280;      // per-wave list capacity
constexpr int ROWS = 256;       // rows per block (8 waves x 32)

struct __align__(16) P1Shared {
    unsigned short sbuf[2][CT * D];  // 64 KB double-buffered B tiles (permuted)
    float sqr[KC];                   // 4 KB (refine)
    float sqrp[KC];                  // 4 KB (scan, permuted)
    int   list[8 * WCAP];            // 40 KB, per-wave segments
    unsigned long long lcand[ROWS];  // 2 KB per-row (score,code) running min
    unsigned short tk[ROWS];         // 512 B final skey thresholds
    int   lcnt[8];
};                                   // ~117.3 KB -> 1 block/CU (forced spread)

// Stage CT codes into dstbuf. Dest linear (global_load_lds rule); SOURCE
// permuted: slot sl holds (code = sl&63, kchunk = sl>>6). Read side: tile t,
// frag kk of lane l sits at slot kk*128 + hi*64 + t*32 + cl -> each 32-lane
// half reads a contiguous 512B run at lane*16 -> conflict-free b128.
__device__ __forceinline__ void stage_issue(const char* __restrict__ srcbase,
                                            unsigned short* __restrict__ dstbuf,
                                            const int (&soff)[4], int tid) {
#pragma unroll
    for (int r = 0; r < 4; ++r) {
        __builtin_amdgcn_global_load_lds(
            (const __attribute__((address_space(1))) void*)(srcbase + soff[r]),
            (__attribute__((address_space(3))) void*)(dstbuf + (tid + r * 512) * 8),
            16, 0, 0);
    }
}

// 256 blocks x 512 thr. Block: 256 rows x 1024 codes. Wave w: rows [w*32,+32).
__global__ __launch_bounds__(512, 1)
void vq_scan(const float* __restrict__ input, const float* __restrict__ weight,
             const unsigned short* __restrict__ wbf, const float* __restrict__ sqr,
             const float* __restrict__ sqrp,
             int* __restrict__ cnt, int* __restrict__ owl,
             unsigned long long* __restrict__ cand) {
    __shared__ P1Shared sh;

    const int tid  = threadIdx.x;
    const int wave = tid >> 6;
    const int lane = tid & 63;
    const int cl   = lane & 31;
    const int hi   = lane >> 5;
    const int row_base_blk = blockIdx.x * ROWS;
    const char* wbfB = (const char*)wbf;

    if (tid < 8) sh.lcnt[tid] = 0;
    if (tid < 256) {
        sh.lcand[tid] = 0xFFFFFFFFFFFFFFFFULL;
        ((float4*)sh.sqr)[tid]  = ((const float4*)sqr)[tid];
        ((float4*)sh.sqrp)[tid] = ((const float4*)sqrp)[tid];
    }

    // per-thread DMA source offsets within a 32 KB stage: slot = tid + r*512;
    // code = slot&63, kchunk = slot>>6; off = code*512 + kchunk*16 bytes.
    int soff[4];
#pragma unroll
    for (int r = 0; r < 4; ++r) {
        const int sl = tid + r * 512;
        soff[r] = (sl & 63) * 512 + (sl >> 6) * 16;
    }

    // Token fragments (B-operand), 32x32x16: col = lane&31, k = kt*16 + hi*8 + j.
    bf16x8 afr[16];
    {
        const float* ar = input + (size_t)(row_base_blk + wave * 32 + cl) * D;
#pragma unroll
        for (int kt = 0; kt < 16; ++kt) {
            const int k0 = kt * 16 + hi * 8;
            float4 f0 = *(const float4*)(ar + k0);
            float4 f1 = *(const float4*)(ar + k0 + 4);
            bf16x8 v;
            v[0] = (short)f2bf(f0.x); v[1] = (short)f2bf(f0.y);
            v[2] = (short)f2bf(f0.z); v[3] = (short)f2bf(f0.w);
            v[4] = (short)f2bf(f1.x); v[5] = (short)f2bf(f1.y);
            v[6] = (short)f2bf(f1.z); v[7] = (short)f2bf(f1.w);
            afr[kt] = v;
        }
    }

    float rmin = 3.4e38f;   // running approx min for this lane's token
    int   wcur = 0;         // per-wave list cursor (wave-uniform register)

    __syncthreads();   // LDS init visible

    stage_issue(wbfB, sh.sbuf[0], soff, tid);   // prefetch stage 0

    for (int s = 0; s < NSTG; ++s) {
        __syncthreads();   // my stage-s loads drained (issued a full stage ago)
        if (s + 1 < NSTG)
            stage_issue(wbfB + (s + 1) * 32768, sh.sbuf[(s + 1) & 1], soff, tid);

        const unsigned short* sbb = sh.sbuf[s & 1];
        const int c0 = s * CT;

#pragma unroll
        for (int t = 0; t < 2; ++t) {          // two 32-code tiles
            // codes as A-operand: slot = kk*128 + hi*64 + t*32 + cl
            const unsigned short* sb = sbb + (size_t)(hi * 64 + t * 32 + cl) * 8;
            f32x16 acc = {0.f,0.f,0.f,0.f, 0.f,0.f,0.f,0.f,
                          0.f,0.f,0.f,0.f, 0.f,0.f,0.f,0.f};
#pragma unroll
            for (int h = 0; h < 2; ++h) {      // b live-range capped at 32 regs
                bf16x8 b[8];
#pragma unroll
                for (int kk = 0; kk < 8; ++kk)
                    b[kk] = *(const bf16x8*)(sb + (size_t)(h * 8 + kk) * 1024);
#pragma unroll
                for (int kk = 0; kk < 8; ++kk)
                    acc = __builtin_amdgcn_mfma_f32_32x32x16_bf16(b[kk], afr[h * 8 + kk], acc, 0, 0, 0);
            }

            // sqrp broadcasts: 16 f32, uniform within each hi half-wave.
            const float4* sp = (const float4*)(sh.sqrp + c0 + t * 32 + hi * 16);
            float4 q0 = sp[0], q1 = sp[1], q2 = sp[2], q3 = sp[3];
            float sc[16];
            sc[0]=q0.x-2.0f*acc[0];   sc[1]=q0.y-2.0f*acc[1];
            sc[2]=q0.z-2.0f*acc[2];   sc[3]=q0.w-2.0f*acc[3];
            sc[4]=q1.x-2.0f*acc[4];   sc[5]=q1.y-2.0f*acc[5];
            sc[6]=q1.z-2.0f*acc[6];   sc[7]=q1.w-2.0f*acc[7];
            sc[8]=q2.x-2.0f*acc[8];   sc[9]=q2.y-2.0f*acc[9];
            sc[10]=q2.z-2.0f*acc[10]; sc[11]=q2.w-2.0f*acc[11];
            sc[12]=q3.x-2.0f*acc[12]; sc[13]=q3.y-2.0f*acc[13];
            sc[14]=q3.z-2.0f*acc[14]; sc[15]=q3.w-2.0f*acc[15];

            // per-token stage min: in-lane tree + one cross-half swap
            float m = fminf(fminf(fminf(sc[0], sc[1]), fminf(sc[2], sc[3])),
                            fminf(fminf(sc[4], sc[5]), fminf(sc[6], sc[7])));
            m = fminf(m, fminf(fminf(fminf(sc[8], sc[9]), fminf(sc[10], sc[11])),
                               fminf(fminf(sc[12], sc[13]), fminf(sc[14], sc[15]))));
            m = fminf(m, __shfl_xor(m, 32, 64));
            rmin = fminf(rmin, m);
            const float thr = rmin + MARGIN;

            // ballot-free emission: flag mask + wave prefix scan + reg cursor
            unsigned m16 = 0u;
#pragma unroll
            for (int r = 0; r < 16; ++r)
                m16 |= (sc[r] <= thr) ? (1u << r) : 0u;
            const int cntl = __popc(m16);
            int incl = cntl;
#pragma unroll
            for (int off = 1; off < 64; off <<= 1) {
                int v = __shfl_up(incl, off, 64);
                if (lane >= off) incl += v;
            }
            const int total = __shfl(incl, 63, 64);
            if (total) {
                const int base = wcur + (incl - cntl);
                int* seg = sh.list + wave * WCAP;
#pragma unroll
                for (int r = 0; r < 16; ++r) {
                    if (m16 & (1u << r)) {
                        const int pos  = base + __popc(m16 & ((1u << r) - 1u));
                        const int code = c0 + t * 32 + (r & 3) + 8 * (r >> 2) + 4 * hi;
                        if (pos < WCAP) {
                            const unsigned skey = fkey(sc[r]) >> 16;
                            seg[pos] = (int)((skey << 16) | ((unsigned)cl << 10)
                                             | (unsigned)code);
                        } else {          // rare: global overflow list
                            int g = atomicAdd(cnt, 1);
                            if (g < OWL_CAP)
                                owl[g] = ((row_base_blk + wave * 32 + cl) << 10) | code;
                        }
                    }
                }
                wcur += total;
            }
        }
    }

    // final per-row skey threshold (rmin identical across hi pair after folds)
    if (hi == 0) {
        unsigned t32 = (fkey(rmin + MARGIN) >> 16) + 1u;
        sh.tk[wave * 32 + cl] = (unsigned short)(t32 > 0xFFFFu ? 0xFFFFu : t32);
    }
    if (lane == 0) sh.lcnt[wave] = (wcur < WCAP) ? wcur : WCAP;

    __syncthreads();   // list + tk complete across waves

    // ---- refine: skip-filtered exact fp32 dot, 16 lanes per candidate ----
    {
        const int sw = tid >> 4;
        const int sl = tid & 15;
        const float4* in4 = (const float4*)input;
        const float4* w4  = (const float4*)weight;
        for (int seg = 0; seg < 8; ++seg) {
            const int n = sh.lcnt[seg];
            const int* lp = sh.list + seg * WCAP;
            for (int e = sw; e < n; e += 32) {
                const unsigned ent = (unsigned)lp[e];
                const int lrow = seg * 32 + (int)((ent >> 10) & 31u);
                if ((ent >> 16) > (unsigned)sh.tk[lrow]) continue;   // skip
                const int code = (int)(ent & 1023u);
                const float4* zr = in4 + (size_t)(row_base_blk + lrow) * 64;
                const float4* wr = w4 + (size_t)code * 64;
                float s = 0.f;
#pragma unroll
                for (int j = 0; j < 4; ++j) {
                    float4 za = zr[sl + 16 * j];
                    float4 wa = wr[sl + 16 * j];
                    s = fmaf(za.x, wa.x, s);
                    s = fmaf(za.y, wa.y, s);
                    s = fmaf(za.z, wa.z, s);
                    s = fmaf(za.w, wa.w, s);
                }
#pragma unroll
                for (int off = 1; off <= 8; off <<= 1) s += __shfl_xor(s, off, 16);
                if (sl == 0) {
                    const float score = sh.sqr[code] - 2.0f * s;
                    unsigned long long key =
                        ((unsigned long long)fkey(score) << 32) | (unsigned int)code;
                    atomicMin(&sh.lcand[lrow], key);
                }
            }
        }
    }
    __syncthreads();

    if (tid < 256) cand[row_base_blk + tid] = sh.lcand[tid];
}

// ---------------- cleanup: exact redo of overflow rows -> cand[] ----------
__global__ __launch_bounds__(256)
void vq_cleanup(const float* __restrict__ input, const float* __restrict__ weight,
                const float* __restrict__ sqr, const int* __restrict__ owl,
                const int* __restrict__ cnt, unsigned long long* __restrict__ cand) {
    const int m = min(*cnt, OWL_CAP);
    if (m == 0) return;
    __shared__ float zrow[D];
    __shared__ unsigned long long best;
    const int tid = threadIdx.x;
    for (int e = blockIdx.x; e < m; e += gridDim.x) {
        const int grow = owl[e] >> 10;
        if (tid == 0) best = 0xFFFFFFFFFFFFFFFFULL;
        if (tid < 64) ((float4*)zrow)[tid] = ((const float4*)input)[(size_t)grow * 64 + tid];
        __syncthreads();
        for (int cc = 0; cc < 4; ++cc) {
            const int code = tid * 4 + cc;
            const float4* wr = (const float4*)weight + (size_t)code * 64;
            float s = 0.f;
            for (int k = 0; k < 64; ++k) {
                float4 wa = wr[k];
                s = fmaf(zrow[4 * k],     wa.x, s);
                s = fmaf(zrow[4 * k + 1], wa.y, s);
                s = fmaf(zrow[4 * k + 2], wa.z, s);
                s = fmaf(zrow[4 * k + 3], wa.w, s);
            }
            const float score = sqr[code] - 2.0f * s;
            unsigned long long key =
                ((unsigned long long)fkey(score) << 32) | (unsigned int)code;
            atomicMin(&best, key);
        }
        __syncthreads();
        if (tid == 0) cand[grow] = best;
        __syncthreads();
    }
}

// ---------------- finish: render outputs from cand[] ----------------
__global__ __launch_bounds__(256)
void vq_finish(const float* __restrict__ weight,
               const unsigned long long* __restrict__ cand,
               float* __restrict__ out) {
    __shared__ int fin[64];
    const int tid  = threadIdx.x;
    const int row0 = blockIdx.x * 64;
    if (tid < 64) {
        int idx = (int)(cand[row0 + tid] & 1023ULL);
        fin[tid] = idx;
        out[IDX_OFF + row0 + tid] = (float)idx;
    }
    __syncthreads();
    const float4* w4 = (const float4*)weight;
    float4* out4 = (float4*)out;
#pragma unroll
    for (int k = 0; k < 16; ++k) {
        int i = tid + k * 256;
        int r = i >> 6, q = i & 63;
        float4 v = w4[(size_t)fin[r] * 64 + q];
        size_t o = (size_t)(row0 + r) * 64 + q;
        out4[o] = v;                    // values
        out4[VEC_OFF / 4 + o] = v;      // vectors
    }
}

extern "C" void kernel_launch(void* const* d_in, const int* in_sizes, int n_in,
                              void* d_out, int out_size, void* d_ws, size_t ws_size,
                              hipStream_t stream) {
    const float* input  = (const float*)d_in[0];   // [64,32,32,256] f32
    const float* weight = (const float*)d_in[1];   // [1024,256] f32
    float* out = (float*)d_out;

    // ws layout (~1.05 MB)
    unsigned short* wbf = (unsigned short*)d_ws;                            // 512 KB
    float* sqr  = (float*)((char*)d_ws + 524288);                           // 4 KB
    float* sqrp = (float*)((char*)d_ws + 528384);                           // 4 KB
    int*   cnt  = (int*)((char*)d_ws + 532480);                             // 4 KB slot
    unsigned long long* cand = (unsigned long long*)((char*)d_ws + 536576); // 512 KB

    // overflow list lives in out's values region; cleanup reads it BEFORE
    // finish (the only writer of out) runs.
    int* owl = (int*)out;

    vq_prep   <<<KC, 64, 0, stream>>>(weight, wbf, sqr, sqrp, cnt);
    vq_scan   <<<N_TOK / ROWS, 512, 0, stream>>>(input, weight, wbf, sqr, sqrp, cnt, owl, cand);
    vq_cleanup<<<256, 256, 0, stream>>>(input, weight, sqr, owl, cnt, cand);
    vq_finish <<<N_TOK / 64, 256, 0, stream>>>(weight, cand, out);
}